// Round 17
// baseline (318.588 us; speedup 1.0000x reference)
//
#include <hip/hip_runtime.h>
#include <hip/hip_bf16.h>
#include <cmath>

#define DIM 512
#define HID 256
#define ROWS_PB 32       // rows per block (100000 = 3125 * 32, no tail)
#define NCHUNK 16        // K chunks of 32

typedef __attribute__((ext_vector_type(8))) short short8;
typedef __attribute__((ext_vector_type(4))) float f32x4;

__device__ __forceinline__ unsigned short f2bf(float f) {
  union { float f; unsigned u; } v; v.f = f;
  unsigned u = v.u;
  return (unsigned short)((u + 0x7FFFu + ((u >> 16) & 1u)) >> 16);
}
__device__ __forceinline__ float bf2f(short h) {
  union { unsigned u; float f; } v;
  v.u = ((unsigned)(unsigned short)h) << 16;
  return v.f;
}

// Pre-swizzle W1 (fp32 [512,256] row-major) into bf16 fragment order:
// w1s short8-idx kg*256 + col (kg = k>>3) = 16B k-octet for one column.
// Quarter q of one kg (cols q*64..+64) is 1 KB contiguous -> linear
// global_load_lds staging.
__global__ void w1_swz_kernel(const float* __restrict__ W1,
                              unsigned short* __restrict__ w1s) {
  int tid = blockIdx.x * blockDim.x + threadIdx.x;
  if (tid >= DIM * HID) return;
  int k = tid / HID;
  int c = tid - k * HID;
  w1s[(((k >> 3) * HID) + c) * 8 + (k & 7)] = f2bf(W1[tid]);
}

__device__ __forceinline__ short8 cvt8(const f32x4 p0, const f32x4 p1) {
  short8 r;
  r[0] = (short)f2bf(p0[0]); r[1] = (short)f2bf(p0[1]);
  r[2] = (short)f2bf(p0[2]); r[3] = (short)f2bf(p0[3]);
  r[4] = (short)f2bf(p1[0]); r[5] = (short)f2bf(p1[1]);
  r[6] = (short)f2bf(p1[2]); r[7] = (short)f2bf(p1[3]);
  return r;
}

__device__ __forceinline__ void wcombine(float wa, const short8 a, float wb,
                                         const short8 b, f32x4& o0, f32x4& o1) {
#pragma unroll
  for (int i = 0; i < 4; ++i) {
    o0[i] = wa * bf2f(a[i]) + wb * bf2f(b[i]);
    o1[i] = wa * bf2f(a[i + 4]) + wb * bf2f(b[i + 4]);
  }
}

// 4 waves / 32 rows. Wave w: src s=w&1, row-tile=w>>1; 16x16x32 MFMA.
// B is time-multiplexed through a 64 KB LDS quarter (4 phases); A (z rows,
// bf16) is loaded ONCE during phase 0 — the only HBM-read phase, with ZERO
// barriers — and retained in 64 VGPRs (af[16]) for phases 1-3, which are
// pure LDS+MFMA. Partial relu-dot logits accumulate across phases (each
// quarter sees full K=512 before its relu). Epilogue: partner-wave af
// exchange through the freed LDS; out written from registers (no HBM reads).
// LDS 64.3 KB + ~130 VGPR -> 2 blocks/CU; block 2's phase-0 HBM overlaps
// block 1's LDS phases.
__global__ __launch_bounds__(256, 2) void fa_main_kernel(
    const float* __restrict__ z1, const float* __restrict__ z2,
    const unsigned short* __restrict__ w1s,
    const float* __restrict__ bias1, const float* __restrict__ W2,
    const float* __restrict__ bias2, float* __restrict__ out, int n) {
  __shared__ char smem[65536 + 256];  // Bq/exchange 64 KB; xs at +65536
  short8* Bq = (short8*)smem;         // [kg 64][col 64] short8
  float* xs = (float*)(smem + 65536); // [src 2][row 32]

  const int t = threadIdx.x;
  const int w = t >> 6;
  const int l = t & 63;
  const int l15 = l & 15, l16 = l >> 4;
  const int s = w & 1;      // source
  const int tile = w >> 1;  // row tile 0..1
  const int row0 = blockIdx.x * ROWS_PB;
  int myrow = row0 + tile * 16 + l15;
  const bool rowok = myrow < n;
  if (!rowok) myrow = n - 1;  // clamp (n%32==0 normally; safety)
  const float* zz = s ? z2 : z1;
  const float* ap = zz + (size_t)myrow * DIM + (l16 << 3);

  // Stage B-quarter q: 64 kg x 1 KB, linear LDS dest, per-lane global src.
  auto STAGE = [&](int q) {
#pragma unroll
    for (int i = 0; i < 16; ++i) {
      const int kg = w + (i << 2);
      const char* gsrc =
          (const char*)w1s + ((size_t)(kg * 256 + q * 64 + l) << 4);
      __builtin_amdgcn_global_load_lds(
          (const __attribute__((address_space(1))) void*)gsrc,
          (__attribute__((address_space(3))) void*)(smem +
                                                    ((kg * 64 + l) << 4)),
          16, 0, 0);
    }
  };

  // Prologue: stage quarter 0; prime the 2-deep A pipeline.
  STAGE(0);
  f32x4 paA[2], paB[2];
  paA[0] = *(const f32x4*)(ap);
  paA[1] = *(const f32x4*)(ap + 4);
  paB[0] = *(const f32x4*)(ap + 32);
  paB[1] = *(const f32x4*)(ap + 36);

  f32x4 acc[4];
#pragma unroll
  for (int f = 0; f < 4; ++f) acc[f] = (f32x4){0.f, 0.f, 0.f, 0.f};
  float part[4] = {0.f, 0.f, 0.f, 0.f};
  short8 af[NCHUNK];

  __syncthreads();  // quarter 0 + A(0),A(1) resident

  // Per-quarter relu-dot accumulate (full K resident per quarter) + acc
  // reset. C/D (16x16): col = q*64 + f*16 + l15, row-in-tile = l16*4 + r.
#define ACCPART(q)                                                        \
  {                                                                       \
    _Pragma("unroll") for (int f = 0; f < 4; ++f) {                       \
      const int cc = ((q) << 6) + (f << 4) + l15;                         \
      const float w2v = W2[cc];                                           \
      const float b1v = bias1[cc];                                        \
      _Pragma("unroll") for (int r = 0; r < 4; ++r) {                     \
        const float hh = acc[f][r] + b1v;                                 \
        part[r] += (hh > 0.f) ? hh * w2v : 0.f;                           \
        acc[f][r] = 0.f;                                                  \
      }                                                                   \
    }                                                                     \
  }

  // ---- Phase 0: the ONLY HBM phase; zero barriers. A streams 2-deep
  // while MFMAs run against the resident quarter; af[] retained.
#pragma unroll
  for (int c = 0; c < NCHUNK; ++c) {
    if (c & 1)
      af[c] = cvt8(paB[0], paB[1]);
    else
      af[c] = cvt8(paA[0], paA[1]);
    if (c + 2 < NCHUNK) {
      const float* apn = ap + ((c + 2) << 5);
      if (c & 1) {
        paB[0] = *(const f32x4*)(apn);
        paB[1] = *(const f32x4*)(apn + 4);
      } else {
        paA[0] = *(const f32x4*)(apn);
        paA[1] = *(const f32x4*)(apn + 4);
      }
    }
    __builtin_amdgcn_sched_barrier(0);  // pin the A-issue above the MFMAs
    const short8* bp = Bq + ((c << 2) + l16) * 64 + l15;
#pragma unroll
    for (int f = 0; f < 4; ++f)
      acc[f] = __builtin_amdgcn_mfma_f32_16x16x32_bf16(af[c], bp[f << 4],
                                                       acc[f], 0, 0, 0);
  }
  ACCPART(0);

  // ---- Phases 1..3: pure LDS + MFMA from retained af. No global loads.
#pragma unroll
  for (int q = 1; q < 4; ++q) {
    __syncthreads();  // all reads of previous quarter complete
    STAGE(q);
    __syncthreads();  // new quarter resident (drains gload_lds)
#pragma unroll
    for (int c = 0; c < NCHUNK; ++c) {
      const short8* bp = Bq + ((c << 2) + l16) * 64 + l15;
#pragma unroll
      for (int f = 0; f < 4; ++f)
        acc[f] = __builtin_amdgcn_mfma_f32_16x16x32_bf16(af[c], bp[f << 4],
                                                         acc[f], 0, 0, 0);
    }
    ACCPART(q);
  }
#undef ACCPART

  // Logit reduce across the 16 lanes of each row group.
#pragma unroll
  for (int r = 0; r < 4; ++r) {
#pragma unroll
    for (int m = 1; m < 16; m <<= 1) part[r] += __shfl_xor(part[r], m, 16);
  }

  __syncthreads();  // all quarter-3 LDS reads done before overwrite

  // Exchange: wave w parks its af (16 KB) at smem + w*16384; logits to xs.
  {
    char* eb = smem + (w << 14) + (l << 4);
#pragma unroll
    for (int c = 0; c < NCHUNK; ++c) *(short8*)(eb + (c << 10)) = af[c];
  }
  if (l15 == 0) {
#pragma unroll
    for (int r = 0; r < 4; ++r)
      xs[(s << 5) + tile * 16 + (l16 << 2) + r] = part[r];
  }
  __syncthreads();

  // Epilogue: out = sx*z1 + sy*z2 from own af + partner's parked af.
  const float x = xs[tile * 16 + l15];
  const float y = xs[32 + tile * 16 + l15];
  const float sx = 1.f / (1.f + __expf(y - x));  // b2 cancels
  const float sy = 1.f - sx;
  const float wOwn = s ? sy : sx;
  const float wOth = s ? sx : sy;
  const char* pb = smem + ((w ^ 1) << 14) + (l << 4);
  float* orow = out + (size_t)myrow * DIM + (l16 << 3);
  if (rowok) {
#pragma unroll
    for (int c = 0; c < NCHUNK; ++c) {
      const short8 po = *(const short8*)(pb + (c << 10));
      f32x4 o0, o1;
      wcombine(wOwn, af[c], wOth, po, o0, o1);
      *(f32x4*)(orow + (c << 5)) = o0;
      *(f32x4*)(orow + (c << 5) + 4) = o1;
    }
  }
}

extern "C" void kernel_launch(void* const* d_in, const int* in_sizes, int n_in,
                              void* d_out, int out_size, void* d_ws,
                              size_t ws_size, hipStream_t stream) {
  const float* z1 = (const float*)d_in[0];
  const float* z2 = (const float*)d_in[1];
  const float* W1 = (const float*)d_in[2];
  const float* b1 = (const float*)d_in[3];
  const float* W2 = (const float*)d_in[4];
  const float* b2 = (const float*)d_in[5];
  float* out = (float*)d_out;
  const int n = in_sizes[0] / DIM;
  unsigned short* w1s = (unsigned short*)d_ws;  // 512*256*2 = 256 KB

  hipLaunchKernelGGL(w1_swz_kernel, dim3((DIM * HID + 255) / 256), dim3(256),
                     0, stream, W1, w1s);
  const int nwg = (n + ROWS_PB - 1) / ROWS_PB;
  hipLaunchKernelGGL(fa_main_kernel, dim3(nwg), dim3(256), 0, stream, z1, z2,
                     w1s, b1, W2, b2, out, n);
}

// Round 18
// 185.125 us; speedup vs baseline: 1.7209x; 1.7209x over previous
//
#include <hip/hip_runtime.h>
#include <hip/hip_bf16.h>
#include <cmath>

#define DIM 512
#define HID 256
#define ROWS_PB 32       // rows per block (100000 = 3125 * 32, no tail)
#define NCHUNK 16        // K chunks of 32
#define CB 16384         // B chunk bytes: 32k * 256c * 2B

typedef __attribute__((ext_vector_type(8))) short short8;
typedef __attribute__((ext_vector_type(4))) float f32x4;
typedef __attribute__((ext_vector_type(4))) unsigned int u32x4;

__device__ __forceinline__ unsigned short f2bf(float f) {
  union { float f; unsigned u; } v; v.f = f;
  unsigned u = v.u;
  return (unsigned short)((u + 0x7FFFu + ((u >> 16) & 1u)) >> 16);
}
__device__ __forceinline__ float bf2f(short h) {
  union { unsigned u; float f; } v;
  v.u = ((unsigned)(unsigned short)h) << 16;
  return v.f;
}

// Pre-swizzle W1 (fp32 [512,256] row-major) into bf16 MFMA fragment order:
// w1s[((k>>3)*HID + c)*8 + (k&7)]. K-chunk c (32 k's) is the contiguous
// 16 KB at byte offset c*16384 — a linear copy.
__global__ void w1_swz_kernel(const float* __restrict__ W1,
                              unsigned short* __restrict__ w1s) {
  int tid = blockIdx.x * blockDim.x + threadIdx.x;
  if (tid >= DIM * HID) return;
  int k = tid / HID;
  int c = tid - k * HID;
  w1s[(((k >> 3) * HID) + c) * 8 + (k & 7)] = f2bf(W1[tid]);
}

__device__ __forceinline__ short8 cvt8(const f32x4 p0, const f32x4 p1) {
  short8 r;
  r[0] = (short)f2bf(p0[0]); r[1] = (short)f2bf(p0[1]);
  r[2] = (short)f2bf(p0[2]); r[3] = (short)f2bf(p0[3]);
  r[4] = (short)f2bf(p1[0]); r[5] = (short)f2bf(p1[1]);
  r[6] = (short)f2bf(p1[2]); r[7] = (short)f2bf(p1[3]);
  return r;
}

__device__ __forceinline__ void wcombine(float wa, const short8 a, float wb,
                                         const short8 b, f32x4& o0, f32x4& o1) {
#pragma unroll
  for (int i = 0; i < 4; ++i) {
    o0[i] = wa * bf2f(a[i]) + wb * bf2f(b[i]);
    o1[i] = wa * bf2f(a[i + 4]) + wb * bf2f(b[i + 4]);
  }
}

// R13 structure + BLOCK-PHASE STAGGER: each block walks the 16 K-chunks
// cyclically starting at a per-block phase c0, so co-resident blocks hit
// their barrier drains at different times and cover each other's stalls.
// (K-chunk accumulation commutes; fp32 reassociation error << threshold.)
__global__ __launch_bounds__(256, 2) void fa_main_kernel(
    const float* __restrict__ z1, const float* __restrict__ z2,
    const unsigned short* __restrict__ w1s,
    const float* __restrict__ bias1, const float* __restrict__ W2,
    const float* __restrict__ bias2, float* __restrict__ out, int n) {
  // Az [src][chunk][tile][lane] short8 = 64 KB; Bs 16 KB (xs aliases Bs
  // after the K-loop). Total 80 KB static.
  __shared__ char smem[81920];
  short8* Az = (short8*)smem;
  char* Bs = smem + 65536;
  float* xs = (float*)(smem + 65536);  // [src][32 rows], used post-K-loop

  const int t = threadIdx.x;
  const int w = t >> 6;
  const int l = t & 63;
  const int l15 = l & 15, l16 = l >> 4;
  const int s = w & 1;    // source
  const int tl = w >> 1;  // row tile 0..1
  const int bid = blockIdx.x;
  const int c0 = (bid + (bid >> 4) + (bid >> 8)) & 15;  // block phase
  const int row0 = bid * ROWS_PB;
  const int myrow = row0 + tl * 16 + l15;
  const bool rok = myrow < n;
  const float* zz = s ? z2 : z1;
  const float* ap = zz + (size_t)myrow * DIM + (l16 << 3);
  const f32x4 zf4 = (f32x4){0.f, 0.f, 0.f, 0.f};

  // T14 B-staging: 16 KB/chunk = 4 x u32x4 per thread.
  u32x4 breg0, breg1, breg2, breg3;
#define BLOAD(c)                                            \
  {                                                         \
    const u32x4* g = (const u32x4*)w1s + (c) * 1024 + t;    \
    breg0 = g[0];                                           \
    breg1 = g[256];                                         \
    breg2 = g[512];                                         \
    breg3 = g[768];                                         \
  }
#define BWRITE()                                            \
  {                                                         \
    u32x4* d = (u32x4*)Bs + t;                              \
    d[0] = breg0;                                           \
    d[256] = breg1;                                         \
    d[512] = breg2;                                         \
    d[768] = breg3;                                         \
  }

  // ---- Phase 1: B[c0] issue, then the A burst (4 groups x 8 indep loads).
  BLOAD(c0);
  __builtin_amdgcn_sched_barrier(0);
#pragma unroll
  for (int g = 0; g < 4; ++g) {
    f32x4 p[4][2];
#pragma unroll
    for (int j = 0; j < 4; ++j) {
      const float* pp = ap + (((g << 2) + j) << 5);
      p[j][0] = rok ? *(const f32x4*)(pp) : zf4;
      p[j][1] = rok ? *(const f32x4*)(pp + 4) : zf4;
    }
#pragma unroll
    for (int j = 0; j < 4; ++j)
      Az[((s * NCHUNK + (g << 2) + j) * 2 + tl) * 64 + l] =
          cvt8(p[j][0], p[j][1]);
  }
  BWRITE();  // waits only breg (landed long ago, L2)
  __syncthreads();  // Az + B[c0] visible

  f32x4 acc[16];
#pragma unroll
  for (int f = 0; f < 16; ++f) acc[f] = zf4;

  // ---- Phase 2: K-loop, L2-only, staggered chunk order c0, c0+1, ...
#pragma unroll
  for (int i = 0; i < NCHUNK; ++i) {
    const int c = (c0 + i) & 15;
    if (i + 1 < NCHUNK) BLOAD((c + 1) & 15);  // early issue (L2)
    __builtin_amdgcn_sched_barrier(0);
    // Batched fragment reads: af + 16 B-frags, all in flight together.
    const short8* bp = (const short8*)Bs + (l16 << 8) + l15;
    const short8 af = Az[((s * NCHUNK + c) * 2 + tl) * 64 + l];
    short8 bf[16];
#pragma unroll
    for (int f = 0; f < 16; ++f) bf[f] = bp[f << 4];
    __builtin_amdgcn_sched_barrier(0);  // reads above, MFMAs below
#pragma unroll
    for (int f = 0; f < 16; ++f)
      acc[f] =
          __builtin_amdgcn_mfma_f32_16x16x32_bf16(af, bf[f], acc[f], 0, 0, 0);
    __syncthreads();  // all reads of Bs done; BLOAD already landed
    if (i + 1 < NCHUNK) BWRITE();
    __syncthreads();  // new B chunk visible
  }

  // ---- Phase 3a: full logit per wave. C/D: col = f*16+l15, row = l16*4+r.
  float part[4] = {0.f, 0.f, 0.f, 0.f};
#pragma unroll
  for (int f = 0; f < 16; ++f) {
    const int cc = (f << 4) + l15;
    const float w2v = W2[cc];
    const float b1v = bias1[cc];
#pragma unroll
    for (int r = 0; r < 4; ++r) {
      const float hh = acc[f][r] + b1v;
      part[r] += (hh > 0.f) ? hh * w2v : 0.f;
    }
  }
#pragma unroll
  for (int r = 0; r < 4; ++r) {
#pragma unroll
    for (int m = 1; m < 16; m <<= 1) part[r] += __shfl_xor(part[r], m, 16);
  }
  if (l15 == 0) {
#pragma unroll
    for (int r = 0; r < 4; ++r)
      xs[s * ROWS_PB + tl * 16 + (l16 << 2) + r] = part[r];
  }
  __syncthreads();

  // ---- Phase 3b: scores + output, entirely from Az (no HBM reads).
  const float x = xs[tl * 16 + l15];
  const float y = xs[ROWS_PB + tl * 16 + l15];
  const float sx = 1.f / (1.f + __expf(y - x));  // b2 cancels
  const float sy = 1.f - sx;
  float* orow = out + (size_t)myrow * DIM + (l16 << 3);
  if (rok) {
#pragma unroll
    for (int j = 0; j < 8; ++j) {
      const int cc = (s << 3) + j;  // this wave covers column chunks s*8..+8
      const short8 a0 = Az[((0 * NCHUNK + cc) * 2 + tl) * 64 + l];
      const short8 a1 = Az[((1 * NCHUNK + cc) * 2 + tl) * 64 + l];
      f32x4 o0, o1;
      wcombine(sx, a0, sy, a1, o0, o1);
      *(f32x4*)(orow + (cc << 5)) = o0;
      *(f32x4*)(orow + (cc << 5) + 4) = o1;
    }
  }
#undef BLOAD
#undef BWRITE
}

extern "C" void kernel_launch(void* const* d_in, const int* in_sizes, int n_in,
                              void* d_out, int out_size, void* d_ws,
                              size_t ws_size, hipStream_t stream) {
  const float* z1 = (const float*)d_in[0];
  const float* z2 = (const float*)d_in[1];
  const float* W1 = (const float*)d_in[2];
  const float* b1 = (const float*)d_in[3];
  const float* W2 = (const float*)d_in[4];
  const float* b2 = (const float*)d_in[5];
  float* out = (float*)d_out;
  const int n = in_sizes[0] / DIM;
  unsigned short* w1s = (unsigned short*)d_ws;  // 512*256*2 = 256 KB

  hipLaunchKernelGGL(w1_swz_kernel, dim3((DIM * HID + 255) / 256), dim3(256),
                     0, stream, W1, w1s);
  const int nwg = (n + ROWS_PB - 1) / ROWS_PB;
  hipLaunchKernelGGL(fa_main_kernel, dim3(nwg), dim3(256), 0, stream, z1, z2,
                     w1s, b1, W2, b2, out, n);
}